// Round 2
// baseline (95.020 us; speedup 1.0000x reference)
//
#include <hip/hip_runtime.h>
#include <math.h>

#define EPSF 1e-8f

constexpr int B = 16;
constexpr int N = 2048;
constexpr int G = 32;              // m-groups per batch -> 16*32 = 512 blocks
constexpr int MB = N / G;          // 64 m-points per block
constexpr int QS = 4;              // n-range split across the 4 waves of a block
constexpr int NQ = N / QS;         // 512 n per thread
constexpr int THREADS = 256;
constexpr int NPART = B * G;       // 512 partial sums

__device__ __forceinline__ void quat_to_mat(const float q[4], float R[3][3]) {
    float nrm = sqrtf(q[0]*q[0] + q[1]*q[1] + q[2]*q[2] + q[3]*q[3]);
    nrm = fmaxf(nrm, EPSF);
    float inv = 1.0f / nrm;
    float w = q[0]*inv, x = q[1]*inv, y = q[2]*inv, z = q[3]*inv;
    R[0][0] = 1.0f - 2.0f*(y*y + z*z);
    R[0][1] = 2.0f*(x*y - w*z);
    R[0][2] = 2.0f*(x*z + w*y);
    R[1][0] = 2.0f*(x*y + w*z);
    R[1][1] = 1.0f - 2.0f*(x*x + z*z);
    R[1][2] = 2.0f*(y*z - w*x);
    R[2][0] = 2.0f*(x*z - w*y);
    R[2][1] = 2.0f*(y*z + w*x);
    R[2][2] = 1.0f - 2.0f*(x*x + y*y);
}

// grid: (B, G), block: 256.
// Block (b,g) computes sum over its 64 m-points of [ min_n l2(n,m) ] and
// writes ONE float to partial[b*G+g]. Min over n is complete within the
// block: wave w covers n in [w*512, (w+1)*512).
__global__ __launch_bounds__(THREADS)
void quat_main_kernel(const float* __restrict__ predq,
                      const float* __restrict__ gtq,
                      const float* __restrict__ points,
                      float* __restrict__ partial) {
    const int b = blockIdx.x;
    const int g = blockIdx.y;
    const int t = threadIdx.x;
    const int mi = t & (MB - 1);    // 0..63  (== lane id)
    const int q  = t >> 6;          // 0..3   (wave id -> n quarter, wave-uniform)

    __shared__ float4 sp[N];        // 32 KB: (px,py,pz,|p|^2) for all n
    __shared__ float redmin[THREADS];
    __shared__ float wsum;

    // ---- combined rotation M = R_gt^T * R_pred ----
    float pq[4], gq[4];
    #pragma unroll
    for (int i = 0; i < 4; ++i) { pq[i] = predq[4*b + i]; gq[i] = gtq[4*b + i]; }
    float Rp[3][3], Rg[3][3];
    quat_to_mat(pq, Rp);
    quat_to_mat(gq, Rg);
    float M[3][3];
    #pragma unroll
    for (int i = 0; i < 3; ++i)
        #pragma unroll
        for (int j = 0; j < 3; ++j) {
            float s = 0.0f;
            #pragma unroll
            for (int c = 0; c < 3; ++c) s = fmaf(Rg[c][i], Rp[c][j], s);
            M[i][j] = s;
        }

    // ---- stage all 2048 n-points to LDS (coalesced global reads) ----
    const float* P = points + (size_t)b * 3 * N;
    #pragma unroll
    for (int i = t; i < N; i += THREADS) {
        float px = P[i];
        float py = P[N + i];
        float pz = P[2*N + i];
        sp[i] = make_float4(px, py, pz, fmaf(px, px, fmaf(py, py, pz*pz)));
    }
    __syncthreads();

    // ---- this thread's m-point ----
    const int m = g * MB + mi;
    const float ax = P[m], ay = P[N + m], az = P[2*N + m];
    const float nx = -2.0f * (M[0][0]*ax + M[0][1]*ay + M[0][2]*az);
    const float ny = -2.0f * (M[1][0]*ax + M[1][1]*ay + M[1][2]*az);
    const float nz = -2.0f * (M[2][0]*ax + M[2][1]*ay + M[2][2]*az);

    // ---- min over this wave's n-quarter (LDS reads are wave-uniform -> broadcast) ----
    float mn = 3.4e38f;
    const int n0 = q * NQ;
    #pragma unroll 8
    for (int n = 0; n < NQ; ++n) {
        float4 p = sp[n0 + n];
        float d = fmaf(p.x, nx, p.w);
        d = fmaf(p.y, ny, d);
        d = fmaf(p.z, nz, d);
        mn = fminf(mn, d);
    }

    // ---- combine the 4 waves' quarter-mins per m, then block-sum 64 values ----
    redmin[t] = mn;
    __syncthreads();
    if (t < MB) {
        float v = fminf(fminf(redmin[t], redmin[t + 64]),
                        fminf(redmin[t + 128], redmin[t + 192]));
        // thread t has mi==t, so (ax,ay,az) here are m-point t's coords
        v += fmaf(ax, ax, fmaf(ay, ay, az*az));
        // wave0 full 64-lane reduce
        #pragma unroll
        for (int o = 32; o > 0; o >>= 1) v += __shfl_down(v, o, 64);
        if (t == 0) wsum = v;
    }
    __syncthreads();
    if (t == 0) partial[b * G + g] = wsum;
}

// 1 block, 512 threads: sum partials -> pt_loss; cos loss; write out directly.
__global__ __launch_bounds__(NPART)
void quat_finalize_kernel(const float* __restrict__ predq,
                          const float* __restrict__ gtq,
                          const float* __restrict__ partial,
                          float* __restrict__ out) {
    const int t = threadIdx.x;
    const int lane = t & 63;
    const int wid  = t >> 6;

    __shared__ float wpart[NPART / 64];   // 8
    __shared__ float csum;

    // ---- pt_loss partial sum ----
    float v = partial[t];
    #pragma unroll
    for (int o = 32; o > 0; o >>= 1) v += __shfl_down(v, o, 64);
    if (lane == 0) wpart[wid] = v;

    // ---- cos loss: threads 0..15, one per batch ----
    float c = 0.0f;
    if (t < B) {
        float pq0 = predq[4*t+0], pq1 = predq[4*t+1], pq2 = predq[4*t+2], pq3 = predq[4*t+3];
        float gq0 = gtq[4*t+0],   gq1 = gtq[4*t+1],   gq2 = gtq[4*t+2],   gq3 = gtq[4*t+3];
        float dot = pq0*gq0 + pq1*gq1 + pq2*gq2 + pq3*gq3;
        float np_ = sqrtf(pq0*pq0 + pq1*pq1 + pq2*pq2 + pq3*pq3);
        float ng_ = sqrtf(gq0*gq0 + gq1*gq1 + gq2*gq2 + gq3*gq3);
        float denom = fmaxf(np_ * ng_, EPSF);
        c = 1.0f - dot / denom;
    }
    if (wid == 0) {
        #pragma unroll
        for (int o = 8; o > 0; o >>= 1) c += __shfl_down(c, o, 64);
        if (t == 0) csum = c;
    }
    __syncthreads();
    if (t == 0) {
        float s = 0.0f;
        #pragma unroll
        for (int i = 0; i < NPART / 64; ++i) s += wpart[i];
        out[0] = csum * (1.0f / (float)B);
        out[1] = s * (1.0f / (float)(B * N));
    }
}

extern "C" void kernel_launch(void* const* d_in, const int* in_sizes, int n_in,
                              void* d_out, int out_size, void* d_ws, size_t ws_size,
                              hipStream_t stream) {
    const float* predq  = (const float*)d_in[0];   // (16,4)
    const float* gtq    = (const float*)d_in[1];   // (16,4)
    const float* points = (const float*)d_in[2];   // (16,3,2048)
    float* out = (float*)d_out;                    // [cos_loss, pt_loss]
    float* partial = (float*)d_ws;                 // NPART floats

    dim3 grid(B, G);
    quat_main_kernel<<<grid, THREADS, 0, stream>>>(predq, gtq, points, partial);
    quat_finalize_kernel<<<1, NPART, 0, stream>>>(predq, gtq, partial, out);
}

// Round 3
// 70.184 us; speedup vs baseline: 1.3539x; 1.3539x over previous
//
#include <hip/hip_runtime.h>
#include <math.h>

#define EPSF 1e-8f

constexpr int B = 16;
constexpr int N = 2048;
constexpr int NCH = 32;            // n-chunks -> grid (16, 32) = 512 blocks (2/CU)
constexpr int NC = N / NCH;        // 64 n-points staged per block
constexpr int THREADS = 256;
constexpr int MPT = N / THREADS;   // 8 m-points per thread

__device__ __forceinline__ void quat_to_mat(const float q[4], float R[3][3]) {
    float nrm = sqrtf(q[0]*q[0] + q[1]*q[1] + q[2]*q[2] + q[3]*q[3]);
    nrm = fmaxf(nrm, EPSF);
    float inv = 1.0f / nrm;
    float w = q[0]*inv, x = q[1]*inv, y = q[2]*inv, z = q[3]*inv;
    R[0][0] = 1.0f - 2.0f*(y*y + z*z);
    R[0][1] = 2.0f*(x*y - w*z);
    R[0][2] = 2.0f*(x*z + w*y);
    R[1][0] = 2.0f*(x*y + w*z);
    R[1][1] = 1.0f - 2.0f*(x*x + z*z);
    R[1][2] = 2.0f*(y*z - w*x);
    R[2][0] = 2.0f*(x*z - w*y);
    R[2][1] = 2.0f*(y*z + w*x);
    R[2][2] = 1.0f - 2.0f*(x*x + y*y);
}

// grid: (B, NCH), block: 256. Each thread: 8 m-points (m = k*256 + t), full
// min over this block's 64-n chunk, written as 8 coalesced partials.
// partial layout: partial[nc*B*N + b*N + m]
__global__ __launch_bounds__(THREADS)
void quat_main_kernel(const float* __restrict__ predq,
                      const float* __restrict__ gtq,
                      const float* __restrict__ points,
                      float* __restrict__ partial,
                      float* __restrict__ out) {
    const int b  = blockIdx.x;
    const int nc = blockIdx.y;
    const int t  = threadIdx.x;

    __shared__ float4 sp[NC];   // 1 KB: (px,py,pz,|p|^2)

    // ---- combined rotation M = R_gt^T * R_pred (wave-uniform) ----
    float pq[4], gq[4];
    #pragma unroll
    for (int i = 0; i < 4; ++i) { pq[i] = predq[4*b + i]; gq[i] = gtq[4*b + i]; }
    float Rp[3][3], Rg[3][3];
    quat_to_mat(pq, Rp);
    quat_to_mat(gq, Rg);
    float M[3][3];
    #pragma unroll
    for (int i = 0; i < 3; ++i)
        #pragma unroll
        for (int j = 0; j < 3; ++j) {
            float s = 0.0f;
            #pragma unroll
            for (int c = 0; c < 3; ++c) s = fmaf(Rg[c][i], Rp[c][j], s);
            M[i][j] = s;
        }

    // ---- one block handles out init + cos loss (stream order protects finalize) ----
    if (b == 0 && nc == 0 && t == 0) {
        float c = 0.0f;
        for (int bb = 0; bb < B; ++bb) {
            float p0 = predq[4*bb+0], p1 = predq[4*bb+1], p2 = predq[4*bb+2], p3 = predq[4*bb+3];
            float g0 = gtq[4*bb+0],   g1 = gtq[4*bb+1],   g2 = gtq[4*bb+2],   g3 = gtq[4*bb+3];
            float dot = p0*g0 + p1*g1 + p2*g2 + p3*g3;
            float np_ = sqrtf(p0*p0 + p1*p1 + p2*p2 + p3*p3);
            float ng_ = sqrtf(g0*g0 + g1*g1 + g2*g2 + g3*g3);
            c += 1.0f - dot / fmaxf(np_ * ng_, EPSF);
        }
        out[0] = c * (1.0f / (float)B);
        out[1] = 0.0f;
    }

    // ---- stage this chunk's 64 n-points ----
    const float* P = points + (size_t)b * 3 * N;
    if (t < NC) {
        int i = nc * NC + t;
        float px = P[i];
        float py = P[N + i];
        float pz = P[2*N + i];
        sp[t] = make_float4(px, py, pz, fmaf(px, px, fmaf(py, py, pz*pz)));
    }
    __syncthreads();

    // ---- per-thread: 8 m-points' coeffs (-2 * M p_m) ----
    float nx[MPT], ny[MPT], nz[MPT], mn[MPT];
    #pragma unroll
    for (int k = 0; k < MPT; ++k) {
        int m = k * THREADS + t;
        float ax = P[m], ay = P[N + m], az = P[2*N + m];
        nx[k] = -2.0f * (M[0][0]*ax + M[0][1]*ay + M[0][2]*az);
        ny[k] = -2.0f * (M[1][0]*ax + M[1][1]*ay + M[1][2]*az);
        nz[k] = -2.0f * (M[2][0]*ax + M[2][1]*ay + M[2][2]*az);
        mn[k] = 3.4e38f;
    }

    // ---- min over chunk: 1 LDS read amortized over 32 VALU ops ----
    #pragma unroll 2
    for (int n = 0; n < NC; ++n) {
        float4 p = sp[n];
        #pragma unroll
        for (int k = 0; k < MPT; ++k) {
            float d = fmaf(p.x, nx[k], p.w);
            d = fmaf(p.y, ny[k], d);
            d = fmaf(p.z, nz[k], d);
            mn[k] = fminf(mn[k], d);
        }
    }

    float* dst = partial + (size_t)nc * B * N + (size_t)b * N;
    #pragma unroll
    for (int k = 0; k < MPT; ++k) dst[k * THREADS + t] = mn[k];
}

// grid: 128, block: 256. Thread i -> (b,m); min over 32 chunk partials,
// add |p_m|^2, block-sum, atomicAdd into out[1] (zeroed by main kernel).
__global__ __launch_bounds__(THREADS)
void quat_finalize_kernel(const float* __restrict__ points,
                          const float* __restrict__ partial,
                          float* __restrict__ out) {
    const int i = blockIdx.x * THREADS + threadIdx.x;   // 0 .. B*N-1
    const int b = i >> 11;
    const int m = i & (N - 1);

    float mn = partial[i];
    #pragma unroll
    for (int nc = 1; nc < NCH; ++nc) mn = fminf(mn, partial[(size_t)nc * B * N + i]);

    const float* P = points + (size_t)b * 3 * N;
    float px = P[m], py = P[N + m], pz = P[2*N + m];
    float v = mn + fmaf(px, px, fmaf(py, py, pz*pz));

    #pragma unroll
    for (int o = 32; o > 0; o >>= 1) v += __shfl_down(v, o, 64);

    __shared__ float wsum[THREADS / 64];
    const int lane = threadIdx.x & 63;
    const int wid  = threadIdx.x >> 6;
    if (lane == 0) wsum[wid] = v;
    __syncthreads();
    if (threadIdx.x == 0) {
        float s = wsum[0] + wsum[1] + wsum[2] + wsum[3];
        atomicAdd(out + 1, s * (1.0f / (float)(B * N)));
    }
}

extern "C" void kernel_launch(void* const* d_in, const int* in_sizes, int n_in,
                              void* d_out, int out_size, void* d_ws, size_t ws_size,
                              hipStream_t stream) {
    const float* predq  = (const float*)d_in[0];   // (16,4)
    const float* gtq    = (const float*)d_in[1];   // (16,4)
    const float* points = (const float*)d_in[2];   // (16,3,2048)
    float* out = (float*)d_out;                    // [cos_loss, pt_loss]
    float* partial = (float*)d_ws;                 // NCH * B * N floats = 4 MB

    dim3 grid(B, NCH);
    quat_main_kernel<<<grid, THREADS, 0, stream>>>(predq, gtq, points, partial, out);
    quat_finalize_kernel<<<B * N / THREADS, THREADS, 0, stream>>>(points, partial, out);
}